// Round 4
// baseline (310.628 us; speedup 1.0000x reference)
//
#include <hip/hip_runtime.h>
#include <math.h>

#define N_ROWS 4096
#define DIM    256
#define P_SZ   5532
#define Q_SZ   5000
#define C_COLS 10532            // P+Q
#define TPAD   10624            // table rows padded to 83*128 (zero-filled)
#define PSTR   10624            // proj row stride in bf16 elems == TPAD (full tiles)
#define NGR    (PSTR / 8)       // 1328 ushort8 granules per proj row
#define K_SEL  701              // HARD_NUM + 1
#define SCALAR 30.0f
#define C2     (SCALAR * 1.4426950408889634f)   // log2(e)*30

typedef __attribute__((ext_vector_type(8))) short   short8;
typedef __attribute__((ext_vector_type(4))) float   float4_t;
typedef __attribute__((ext_vector_type(4))) unsigned short ushort4_t;
typedef __attribute__((ext_vector_type(8))) unsigned short ushort8_t;

// ---------------- helpers ----------------
__device__ __forceinline__ unsigned short f2bf(float f) {   // fp32 -> bf16 RNE
    unsigned u = __float_as_uint(f);
    unsigned r = u + 0x7FFFu + ((u >> 16) & 1u);
    return (unsigned short)(r >> 16);
}
__device__ __forceinline__ float bf2f(unsigned short u) {
    return __uint_as_float((unsigned)u << 16);
}
__device__ __forceinline__ unsigned key16(unsigned short u) { // order-preserving key
    return (u & 0x8000u) ? (unsigned)(~u & 0xFFFFu) : (unsigned)(u | 0x8000u);
}
__device__ __forceinline__ void gload16(const void* g, void* l) {
    __builtin_amdgcn_global_load_lds(
        (const __attribute__((address_space(1))) unsigned int*)g,
        (__attribute__((address_space(3))) unsigned int*)l, 16, 0, 0);
}

// ---------------- fp32 -> bf16 pre-conversion (inputs + padded table) ----------------
#define NIN_G  (N_ROWS * DIM / 4)       // 262144 float4 granules
#define NTAB_G (TPAD * DIM / 4)         // 679936

__global__ __launch_bounds__(256) void convert_bf16(
    const float* __restrict__ inputs, const float* __restrict__ lut,
    const float* __restrict__ cq, unsigned short* __restrict__ in_bf,
    unsigned short* __restrict__ tab_bf)
{
    const int g = blockIdx.x * 256 + threadIdx.x;
    if (g >= NIN_G + NTAB_G) return;
    float4_t v;
    unsigned short* dst;
    if (g < NIN_G) {
        v = *(const float4_t*)&inputs[(size_t)g * 4];
        dst = in_bf + (size_t)g * 4;
    } else {
        const int t = g - NIN_G;
        const int row = t >> 6;                 // /(DIM/4)
        const int c4  = (t & 63) * 4;
        if (row < P_SZ)        v = *(const float4_t*)&lut[(size_t)row * DIM + c4];
        else if (row < C_COLS) v = *(const float4_t*)&cq[(size_t)(row - P_SZ) * DIM + c4];
        else                   v = (float4_t){0.f, 0.f, 0.f, 0.f};
        dst = tab_bf + (size_t)t * 4;
    }
    ushort4_t h = { f2bf(v.x), f2bf(v.y), f2bf(v.z), f2bf(v.w) };
    *(ushort4_t*)dst = h;
}

// ---------------- bf16 MFMA GEMM: proj(bf16) = (in @ tab^T) * rel ----------------
#define NWG_X 83
#define NWG_Y 32
#define NWG   (NWG_X * NWG_Y)   // 2656, divisible by 8
#define CSTR  132               // C-tile LDS row stride in elems (264 B, conflict-free)

__global__ __launch_bounds__(256) void gemm_proj(
    const unsigned short* __restrict__ in_bf,
    const unsigned short* __restrict__ tab_bf,
    const float* __restrict__ rel,
    unsigned short* __restrict__ proj)
{
    // union: K-loop stage tiles (2 x 16 KB) / epilogue C-tile (128 x 264 B)
    __shared__ __align__(16) unsigned short smem[128 * CSTR];   // 33792 B
    unsigned short* At = smem;                 // elem (r,k) at byte r*128 + ((k*2)^((r&7)<<4))
    unsigned short* Bt = smem + 128 * 64;

    const int tid  = threadIdx.x;
    const int lane = tid & 63, wid = tid >> 6;
    const int wm = wid >> 1, wn = wid & 1;

    // XCD-bijective swizzle, col-major decode: each XCD chunk keeps full A in L2
    const int phys = blockIdx.x;
    const int wg   = (phys & 7) * (NWG / 8) + (phys >> 3);
    const int bx   = wg >> 5;               // 0..82 col-block
    const int by   = wg & 31;               // 0..31 row-block
    const int row0 = by * 128, col0 = bx * 128;

    float4_t acc[4][4];
    #pragma unroll
    for (int i = 0; i < 4; ++i)
        #pragma unroll
        for (int j = 0; j < 4; ++j)
            acc[i][j] = (float4_t){0.f, 0.f, 0.f, 0.f};

    for (int k0 = 0; k0 < DIM; k0 += 64) {
        // stage: linear LDS dest + inverse-swizzled global source (16B granules)
        #pragma unroll
        for (int it = 0; it < 4; ++it) {
            const int g  = it * 256 + tid;       // granule: LDS byte = g*16
            const int r  = g >> 3;               // 0..127
            const int kb = ((g & 7) * 16) ^ ((r & 7) << 4);   // src byte within row
            gload16(in_bf  + (size_t)(row0 + r) * DIM + k0 + (kb >> 1),
                    (char*)At + g * 16);
            gload16(tab_bf + (size_t)(col0 + r) * DIM + k0 + (kb >> 1),
                    (char*)Bt + g * 16);
        }
        __syncthreads();

        #pragma unroll
        for (int kk = 0; kk < 2; ++kk) {
            const int krow = lane & 15;
            const int kb   = kk * 64 + ((lane >> 4) << 4);
            short8 af[4], bfr[4];
            #pragma unroll
            for (int i = 0; i < 4; ++i) {
                const int r = wm * 64 + i * 16 + krow;
                af[i] = *(const short8*)((const char*)At + (r * 128 + (kb ^ ((r & 7) << 4))));
            }
            #pragma unroll
            for (int j = 0; j < 4; ++j) {
                const int r = wn * 64 + j * 16 + krow;
                bfr[j] = *(const short8*)((const char*)Bt + (r * 128 + (kb ^ ((r & 7) << 4))));
            }
            #pragma unroll
            for (int i = 0; i < 4; ++i)
                #pragma unroll
                for (int j = 0; j < 4; ++j)
                    acc[i][j] = __builtin_amdgcn_mfma_f32_16x16x32_bf16(af[i], bfr[j], acc[i][j], 0, 0, 0);
        }
        __syncthreads();
    }

    // epilogue: C layout col=lane&15, row=(lane>>4)*4+rr  [m89]
    // stage bf16 C-tile in LDS (row stride CSTR), then coalesced 16B stores
    const int lr = (lane >> 4) << 2;
    const int lc = lane & 15;
    #pragma unroll
    for (int j = 0; j < 4; ++j) {
        const int cl  = wn * 64 + j * 16 + lc;        // tile-local col
        const int col = col0 + cl;
        const bool pad = (col >= C_COLS);
        const float rl = pad ? 0.f : rel[col];
        #pragma unroll
        for (int i = 0; i < 4; ++i) {
            const int rbase = wm * 64 + i * 16 + lr;  // tile-local row
            #pragma unroll
            for (int rr = 0; rr < 4; ++rr)
                smem[(rbase + rr) * CSTR + cl] =
                    pad ? (unsigned short)0xFF80u : f2bf(acc[i][j][rr] * rl);
        }
    }
    __syncthreads();
    // 128 rows x 256 B: granule g -> row g>>4, 16B chunk (g&15)
    #pragma unroll
    for (int it = 0; it < 8; ++it) {
        const int g = it * 256 + tid;
        const int r = g >> 4;
        const int c8 = (g & 15) * 8;                  // col in elems
        *(ushort8_t*)(proj + (size_t)(row0 + r) * PSTR + col0 + c8) =
            *(const ushort8_t*)&smem[r * CSTR + c8];
    }
}

// ---------------- per-row: 2-sweep radix select + fused masked LSE ----------------
// stabilizer m = 1.0 fixed (|proj| <= 1), so exp sums fold into the histogram pass
__global__ __launch_bounds__(256) void row_loss_kernel(
    const unsigned short* __restrict__ proj, const int* __restrict__ labels,
    float* __restrict__ row_loss)
{
    __shared__ unsigned hist[2048];     // counts, key bits [15:5]
    __shared__ float    bexp[2048];     // per-bin sum of exp2(C2*(v-1))
    __shared__ unsigned h2[32];
    __shared__ float    e2[32];
    __shared__ unsigned wsum[4];
    __shared__ float    fsum[4];
    __shared__ unsigned sel_b, sel_k;
    __shared__ float    sel_major, sel_minor;

    const int tid = threadIdx.x, lane = tid & 63, wid = tid >> 6;
    const int row = blockIdx.x;
    const ushort8_t* prow = (const ushort8_t*)(proj + (size_t)row * PSTR);

    #pragma unroll
    for (int i = tid; i < 2048; i += 256) { hist[i] = 0; bexp[i] = 0.f; }
    if (tid < 32) { h2[tid] = 0; e2[tid] = 0.f; }
    __syncthreads();

    // ---- sweep 1: histogram counts + per-bin exp sums
    for (int g = tid; g < NGR; g += 256) {
        const ushort8_t v = prow[g];
        #pragma unroll
        for (int e = 0; e < 8; ++e) {
            const unsigned key = key16(v[e]);
            const float ex = exp2f(C2 * (bf2f(v[e]) - 1.0f));
            atomicAdd(&hist[key >> 5], 1u);
            atomicAdd(&bexp[key >> 5], ex);
        }
    }
    __syncthreads();

    // ---- scan: find bin b1 of the K_SEL-th largest; float suffix above it
    {
        const int t8 = tid * 8;
        unsigned s = 0; float f = 0.f;
        #pragma unroll
        for (int b = 0; b < 8; ++b) { s += hist[t8 + b]; f += bexp[t8 + b]; }
        // wave-inclusive suffix (from higher lanes)
        unsigned ic = s; float fc = f;
        #pragma unroll
        for (int off = 1; off < 64; off <<= 1) {
            const unsigned tc = __shfl_down(ic, off, 64);
            const float    tf = __shfl_down(fc, off, 64);
            if (lane + off < 64) { ic += tc; fc += tf; }
        }
        if (lane == 0) { wsum[wid] = ic; fsum[wid] = fc; }
        __syncthreads();
        unsigned cum = ic - s; float fcum = fc - f;    // above within wave
        for (int w = wid + 1; w < 4; ++w) { cum += wsum[w]; fcum += fsum[w]; }
        #pragma unroll
        for (int b = 7; b >= 0; --b) {
            const unsigned c = hist[t8 + b];
            if (cum < K_SEL && cum + c >= K_SEL) {
                sel_b = (unsigned)(t8 + b); sel_k = K_SEL - cum; sel_major = fcum;
            }
            cum += c; fcum += bexp[t8 + b];
        }
    }
    __syncthreads();
    const unsigned b1 = sel_b;
    const unsigned k2 = sel_k;
    __syncthreads();

    // ---- sweep 2: 32 sub-bins (key bits [4:0]) among prefix matches (re-read via L2)
    for (int g = tid; g < NGR; g += 256) {
        const ushort8_t v = prow[g];
        #pragma unroll
        for (int e = 0; e < 8; ++e) {
            const unsigned key = key16(v[e]);
            if ((key >> 5) == b1) {
                atomicAdd(&h2[key & 31u], 1u);
                atomicAdd(&e2[key & 31u], exp2f(C2 * (bf2f(v[e]) - 1.0f)));
            }
        }
    }
    __syncthreads();
    if (wid == 0) {
        const unsigned c = (lane < 32) ? h2[lane] : 0u;
        const float    f = (lane < 32) ? e2[lane] : 0.f;
        unsigned ic = c; float fc = f;
        #pragma unroll
        for (int off = 1; off < 64; off <<= 1) {
            const unsigned tc = __shfl_down(ic, off, 64);
            const float    tf = __shfl_down(fc, off, 64);
            if (lane + off < 64) { ic += tc; fc += tf; }
        }
        const unsigned above = ic - c;
        if (lane < 32 && above < k2 && above + c >= k2) {
            sel_b = (unsigned)lane; sel_minor = fc;    // subkeys >= lane (ties included)
        }
    }
    __syncthreads();

    if (tid == 0) {
        const unsigned bkey = (b1 << 5) | sel_b;
        float total = sel_major + sel_minor;
        const unsigned short ul = *(const unsigned short*)
            ((const unsigned short*)prow + labels[row]);   // label < P_SZ
        const float pl = bf2f(ul);
        if (key16(ul) < bkey) total += exp2f(C2 * (pl - 1.0f));
        row_loss[row] = SCALAR * 1.0f + logf(total) - SCALAR * pl;
    }
}

// ---------------- final mean ----------------
__global__ __launch_bounds__(256) void final_reduce(
    const float* __restrict__ row_loss, float* __restrict__ out)
{
    __shared__ float fred[4];
    const int tid = threadIdx.x, lane = tid & 63, wid = tid >> 6;
    float s = 0.f;
    for (int i = tid; i < N_ROWS; i += 256) s += row_loss[i];
    #pragma unroll
    for (int off = 1; off < 64; off <<= 1) {
        const float t = __shfl_down(s, off, 64);
        if (lane + off < 64) s += t;
    }
    if (lane == 0) fred[wid] = s;
    __syncthreads();
    if (tid == 0) out[0] = (fred[0] + fred[1] + fred[2] + fred[3]) / (float)N_ROWS;
}

extern "C" void kernel_launch(void* const* d_in, const int* in_sizes, int n_in,
                              void* d_out, int out_size, void* d_ws, size_t ws_size,
                              hipStream_t stream) {
    const float* inputs = (const float*)d_in[0];
    const int*   labels = (const int*)d_in[1];
    const float* lut    = (const float*)d_in[2];
    const float* cq     = (const float*)d_in[3];
    const float* rel    = (const float*)d_in[4];
    float* out = (float*)d_out;

    // ws: in_bf [4096*256] | tab_bf [10624*256] | proj [4096*10624] bf16 | row_loss
    unsigned short* in_bf  = (unsigned short*)d_ws;
    unsigned short* tab_bf = in_bf  + (size_t)N_ROWS * DIM;
    unsigned short* proj   = tab_bf + (size_t)TPAD * DIM;
    float* rl_buf = (float*)(proj + (size_t)N_ROWS * PSTR);

    convert_bf16<<<(NIN_G + NTAB_G) / 256, 256, 0, stream>>>(inputs, lut, cq, in_bf, tab_bf);
    gemm_proj<<<NWG, 256, 0, stream>>>(in_bf, tab_bf, rel, proj);
    row_loss_kernel<<<N_ROWS, 256, 0, stream>>>(proj, labels, rl_buf);
    final_reduce<<<1, 256, 0, stream>>>(rl_buf, out);
}

// Round 5
// 107.368 us; speedup vs baseline: 2.8931x; 2.8931x over previous
//
#include <hip/hip_runtime.h>
#include <math.h>

#define N_ROWS 4096
#define DIM    256
#define P_SZ   5532
#define Q_SZ   5000
#define C_COLS 10532            // P+Q
#define TPAD   10624            // table rows padded to 83*128 (zero-filled)
#define PSTR   10624            // proj row stride in bf16 elems == TPAD (full tiles)
#define NGR    (PSTR / 8)       // 1328 ushort8 granules per proj row
#define K_SEL  701              // HARD_NUM + 1
#define SCALAR 30.0f
#define C2     (SCALAR * 1.4426950408889634f)   // log2(e)*30

typedef __attribute__((ext_vector_type(8))) short   short8;
typedef __attribute__((ext_vector_type(4))) float   float4_t;
typedef __attribute__((ext_vector_type(4))) unsigned short ushort4_t;
typedef __attribute__((ext_vector_type(8))) unsigned short ushort8_t;

// ---------------- helpers ----------------
__device__ __forceinline__ unsigned short f2bf(float f) {   // fp32 -> bf16 RNE
    unsigned u = __float_as_uint(f);
    unsigned r = u + 0x7FFFu + ((u >> 16) & 1u);
    return (unsigned short)(r >> 16);
}
__device__ __forceinline__ float bf2f(unsigned short u) {
    return __uint_as_float((unsigned)u << 16);
}
__device__ __forceinline__ unsigned key16(unsigned short u) { // order-preserving key
    return (u & 0x8000u) ? (unsigned)(~u & 0xFFFFu) : (unsigned)(u | 0x8000u);
}
__device__ __forceinline__ void gload16(const void* g, void* l) {
    __builtin_amdgcn_global_load_lds(
        (const __attribute__((address_space(1))) unsigned int*)g,
        (__attribute__((address_space(3))) unsigned int*)l, 16, 0, 0);
}

// ---------------- fp32 -> bf16 pre-conversion (inputs + padded table) ----------------
#define NIN_G  (N_ROWS * DIM / 4)       // 262144 float4 granules
#define NTAB_G (TPAD * DIM / 4)         // 679936

__global__ __launch_bounds__(256) void convert_bf16(
    const float* __restrict__ inputs, const float* __restrict__ lut,
    const float* __restrict__ cq, unsigned short* __restrict__ in_bf,
    unsigned short* __restrict__ tab_bf)
{
    const int g = blockIdx.x * 256 + threadIdx.x;
    if (g >= NIN_G + NTAB_G) return;
    float4_t v;
    unsigned short* dst;
    if (g < NIN_G) {
        v = *(const float4_t*)&inputs[(size_t)g * 4];
        dst = in_bf + (size_t)g * 4;
    } else {
        const int t = g - NIN_G;
        const int row = t >> 6;                 // /(DIM/4)
        const int c4  = (t & 63) * 4;
        if (row < P_SZ)        v = *(const float4_t*)&lut[(size_t)row * DIM + c4];
        else if (row < C_COLS) v = *(const float4_t*)&cq[(size_t)(row - P_SZ) * DIM + c4];
        else                   v = (float4_t){0.f, 0.f, 0.f, 0.f};
        dst = tab_bf + (size_t)t * 4;
    }
    ushort4_t h = { f2bf(v.x), f2bf(v.y), f2bf(v.z), f2bf(v.w) };
    *(ushort4_t*)dst = h;
}

// ---------------- bf16 MFMA GEMM: proj(bf16) = (in @ tab^T) * rel ----------------
#define NWG_X 83
#define NWG_Y 32
#define NWG   (NWG_X * NWG_Y)   // 2656, divisible by 8
#define CSTR  132               // C-tile LDS row stride in elems (264 B, conflict-free)

__global__ __launch_bounds__(256) void gemm_proj(
    const unsigned short* __restrict__ in_bf,
    const unsigned short* __restrict__ tab_bf,
    const float* __restrict__ rel,
    unsigned short* __restrict__ proj)
{
    // union: K-loop stage tiles (2 x 16 KB) / epilogue C-tile (128 x 264 B)
    __shared__ __align__(16) unsigned short smem[128 * CSTR];   // 33792 B
    unsigned short* At = smem;                 // elem (r,k) at byte r*128 + ((k*2)^((r&7)<<4))
    unsigned short* Bt = smem + 128 * 64;

    const int tid  = threadIdx.x;
    const int lane = tid & 63, wid = tid >> 6;
    const int wm = wid >> 1, wn = wid & 1;

    // XCD-bijective swizzle, col-major decode: each XCD chunk keeps full A in L2
    const int phys = blockIdx.x;
    const int wg   = (phys & 7) * (NWG / 8) + (phys >> 3);
    const int bx   = wg >> 5;               // 0..82 col-block
    const int by   = wg & 31;               // 0..31 row-block
    const int row0 = by * 128, col0 = bx * 128;

    float4_t acc[4][4];
    #pragma unroll
    for (int i = 0; i < 4; ++i)
        #pragma unroll
        for (int j = 0; j < 4; ++j)
            acc[i][j] = (float4_t){0.f, 0.f, 0.f, 0.f};

    for (int k0 = 0; k0 < DIM; k0 += 64) {
        // stage: linear LDS dest + inverse-swizzled global source (16B granules)
        #pragma unroll
        for (int it = 0; it < 4; ++it) {
            const int g  = it * 256 + tid;       // granule: LDS byte = g*16
            const int r  = g >> 3;               // 0..127
            const int kb = ((g & 7) * 16) ^ ((r & 7) << 4);   // src byte within row
            gload16(in_bf  + (size_t)(row0 + r) * DIM + k0 + (kb >> 1),
                    (char*)At + g * 16);
            gload16(tab_bf + (size_t)(col0 + r) * DIM + k0 + (kb >> 1),
                    (char*)Bt + g * 16);
        }
        __syncthreads();

        #pragma unroll
        for (int kk = 0; kk < 2; ++kk) {
            const int krow = lane & 15;
            const int kb   = kk * 64 + ((lane >> 4) << 4);
            short8 af[4], bfr[4];
            #pragma unroll
            for (int i = 0; i < 4; ++i) {
                const int r = wm * 64 + i * 16 + krow;
                af[i] = *(const short8*)((const char*)At + (r * 128 + (kb ^ ((r & 7) << 4))));
            }
            #pragma unroll
            for (int j = 0; j < 4; ++j) {
                const int r = wn * 64 + j * 16 + krow;
                bfr[j] = *(const short8*)((const char*)Bt + (r * 128 + (kb ^ ((r & 7) << 4))));
            }
            #pragma unroll
            for (int i = 0; i < 4; ++i)
                #pragma unroll
                for (int j = 0; j < 4; ++j)
                    acc[i][j] = __builtin_amdgcn_mfma_f32_16x16x32_bf16(af[i], bfr[j], acc[i][j], 0, 0, 0);
        }
        __syncthreads();
    }

    // epilogue: C layout col=lane&15, row=(lane>>4)*4+rr  [m89]
    // stage bf16 C-tile in LDS (row stride CSTR), then coalesced 16B stores
    const int lr = (lane >> 4) << 2;
    const int lc = lane & 15;
    #pragma unroll
    for (int j = 0; j < 4; ++j) {
        const int cl  = wn * 64 + j * 16 + lc;        // tile-local col
        const int col = col0 + cl;
        const bool pad = (col >= C_COLS);
        const float rl = pad ? 0.f : rel[col];
        #pragma unroll
        for (int i = 0; i < 4; ++i) {
            const int rbase = wm * 64 + i * 16 + lr;  // tile-local row
            #pragma unroll
            for (int rr = 0; rr < 4; ++rr)
                smem[(rbase + rr) * CSTR + cl] =
                    pad ? (unsigned short)0xFF80u : f2bf(acc[i][j][rr] * rl);
        }
    }
    __syncthreads();
    // 128 rows x 256 B: granule g -> row g>>4, 16B chunk (g&15)
    #pragma unroll
    for (int it = 0; it < 8; ++it) {
        const int g = it * 256 + tid;
        const int r = g >> 4;
        const int c8 = (g & 15) * 8;                  // col in elems
        *(ushort8_t*)(proj + (size_t)(row0 + r) * PSTR + col0 + c8) =
            *(const ushort8_t*)&smem[r * CSTR + c8];
    }
}

// ---------------- per-row: 2-sweep radix select + masked LSE ----------------
// stabilizer m = 1.0 fixed (|proj| <= 1); count-only LDS atomics (native u32);
// exp sums in registers except the ~hist[b1] boundary-bin elements (32 small bins)
__global__ __launch_bounds__(256) void row_loss_kernel(
    const unsigned short* __restrict__ proj, const int* __restrict__ labels,
    float* __restrict__ row_loss)
{
    __shared__ __align__(16) unsigned short vals[PSTR];   // 21248 B
    __shared__ unsigned hist[2048];                        // 8 KB, key bits [15:5]
    __shared__ unsigned h2[32];
    __shared__ float    e2[32];
    __shared__ unsigned wsum[4];
    __shared__ float    fsum[4];
    __shared__ unsigned sel_bin, sel_k, sel_sub;
    __shared__ float    sel_minor;

    const int tid = threadIdx.x, lane = tid & 63, wid = tid >> 6;
    const int row = blockIdx.x;
    const ushort8_t* prow = (const ushort8_t*)(proj + (size_t)row * PSTR);

    for (int i = tid; i < 2048; i += 256) hist[i] = 0;
    if (tid < 32) { h2[tid] = 0; e2[tid] = 0.f; }
    __syncthreads();

    // ---- sweep 1: stage row in LDS + count histogram (native u32 atomics)
    for (int g = tid; g < NGR; g += 256) {
        const ushort8_t v = prow[g];
        *(ushort8_t*)&vals[g * 8] = v;
        #pragma unroll
        for (int e = 0; e < 8; ++e)
            atomicAdd(&hist[key16(v[e]) >> 5], 1u);
    }
    __syncthreads();

    // ---- scan: bin of the K_SEL-th largest + residual rank
    {
        const int t8 = tid * 8;
        unsigned s = 0;
        #pragma unroll
        for (int b = 0; b < 8; ++b) s += hist[t8 + b];
        unsigned incl = s;
        #pragma unroll
        for (int off = 1; off < 64; off <<= 1) {
            const unsigned t = __shfl_down(incl, off, 64);
            if (lane + off < 64) incl += t;
        }
        if (lane == 0) wsum[wid] = incl;
        __syncthreads();
        unsigned cum = incl - s;                       // above within wave
        for (int w = wid + 1; w < 4; ++w) cum += wsum[w];
        #pragma unroll
        for (int b = 7; b >= 0; --b) {
            const unsigned c = hist[t8 + b];
            if (cum < K_SEL && cum + c >= K_SEL) {
                sel_bin = (unsigned)(t8 + b); sel_k = K_SEL - cum;
            }
            cum += c;
        }
    }
    __syncthreads();
    const unsigned b1 = sel_bin;
    const unsigned k2 = sel_k;

    // ---- sweep 2 (LDS): reg-accumulate exp for bins > b1; tiny atomics for bin b1
    float above = 0.f;
    for (int g = tid; g < NGR; g += 256) {
        const ushort8_t v = *(const ushort8_t*)&vals[g * 8];
        #pragma unroll
        for (int e = 0; e < 8; ++e) {
            const unsigned key = key16(v[e]);
            const unsigned bin = key >> 5;
            if (bin > b1) {
                above += exp2f(C2 * (bf2f(v[e]) - 1.0f));
            } else if (bin == b1) {
                atomicAdd(&h2[key & 31u], 1u);
                atomicAdd(&e2[key & 31u], exp2f(C2 * (bf2f(v[e]) - 1.0f)));
            }
        }
    }
    // block-reduce 'above'
    #pragma unroll
    for (int off = 1; off < 64; off <<= 1) {
        const float t = __shfl_down(above, off, 64);
        if (lane + off < 64) above += t;
    }
    if (lane == 0) fsum[wid] = above;
    __syncthreads();

    // ---- sub-scan: 32 bins, key bits [4:0]
    if (wid == 0) {
        const unsigned c = (lane < 32) ? h2[lane] : 0u;
        const float    f = (lane < 32) ? e2[lane] : 0.f;
        unsigned ic = c; float fc = f;
        #pragma unroll
        for (int off = 1; off < 64; off <<= 1) {
            const unsigned tc = __shfl_down(ic, off, 64);
            const float    tf = __shfl_down(fc, off, 64);
            if (lane + off < 64) { ic += tc; fc += tf; }
        }
        const unsigned abv = ic - c;
        if (lane < 32 && abv < k2 && abv + c >= k2) {
            sel_sub = (unsigned)lane; sel_minor = fc;   // inclusive: all ties masked
        }
    }
    __syncthreads();

    if (tid == 0) {
        const unsigned bkey = (b1 << 5) | sel_sub;
        float total = fsum[0] + fsum[1] + fsum[2] + fsum[3] + sel_minor;
        const unsigned short ul = vals[labels[row]];    // label < P_SZ
        const float pl = bf2f(ul);
        if (key16(ul) < bkey) total += exp2f(C2 * (pl - 1.0f));
        row_loss[row] = SCALAR * 1.0f + logf(total) - SCALAR * pl;
    }
}

// ---------------- final mean ----------------
__global__ __launch_bounds__(256) void final_reduce(
    const float* __restrict__ row_loss, float* __restrict__ out)
{
    __shared__ float fred[4];
    const int tid = threadIdx.x, lane = tid & 63, wid = tid >> 6;
    float s = 0.f;
    for (int i = tid; i < N_ROWS; i += 256) s += row_loss[i];
    #pragma unroll
    for (int off = 1; off < 64; off <<= 1) {
        const float t = __shfl_down(s, off, 64);
        if (lane + off < 64) s += t;
    }
    if (lane == 0) fred[wid] = s;
    __syncthreads();
    if (tid == 0) out[0] = (fred[0] + fred[1] + fred[2] + fred[3]) / (float)N_ROWS;
}

extern "C" void kernel_launch(void* const* d_in, const int* in_sizes, int n_in,
                              void* d_out, int out_size, void* d_ws, size_t ws_size,
                              hipStream_t stream) {
    const float* inputs = (const float*)d_in[0];
    const int*   labels = (const int*)d_in[1];
    const float* lut    = (const float*)d_in[2];
    const float* cq     = (const float*)d_in[3];
    const float* rel    = (const float*)d_in[4];
    float* out = (float*)d_out;

    // ws: in_bf [4096*256] | tab_bf [10624*256] | proj [4096*10624] bf16 | row_loss
    unsigned short* in_bf  = (unsigned short*)d_ws;
    unsigned short* tab_bf = in_bf  + (size_t)N_ROWS * DIM;
    unsigned short* proj   = tab_bf + (size_t)TPAD * DIM;
    float* rl_buf = (float*)(proj + (size_t)N_ROWS * PSTR);

    convert_bf16<<<(NIN_G + NTAB_G) / 256, 256, 0, stream>>>(inputs, lut, cq, in_bf, tab_bf);
    gemm_proj<<<NWG, 256, 0, stream>>>(in_bf, tab_bf, rel, proj);
    row_loss_kernel<<<N_ROWS, 256, 0, stream>>>(proj, labels, rl_buf);
    final_reduce<<<1, 256, 0, stream>>>(rl_buf, out);
}

// Round 6
// 103.528 us; speedup vs baseline: 3.0004x; 1.0371x over previous
//
#include <hip/hip_runtime.h>
#include <math.h>

#define N_ROWS 4096
#define DIM    256
#define P_SZ   5532
#define Q_SZ   5000
#define C_COLS 10532            // P+Q
#define TPAD   10624            // table rows padded to 83*128 (zero-filled)
#define PSTR   10624            // proj row stride in u16 elems == TPAD (full tiles)
#define NGR    (PSTR / 8)       // 1328 ushort8 granules per proj row
#define K_SEL  701              // HARD_NUM + 1
#define SCALAR 30.0f
#define C2     (SCALAR * 1.4426950408889634f)   // log2(e)*30

typedef __attribute__((ext_vector_type(8))) short   short8;
typedef __attribute__((ext_vector_type(4))) float   float4_t;
typedef __attribute__((ext_vector_type(4))) unsigned short ushort4_t;
typedef __attribute__((ext_vector_type(8))) unsigned short ushort8_t;

// ---------------- helpers ----------------
__device__ __forceinline__ unsigned short f2bf(float f) {   // fp32 -> bf16 RNE
    unsigned u = __float_as_uint(f);
    unsigned r = u + 0x7FFFu + ((u >> 16) & 1u);
    return (unsigned short)(r >> 16);
}
__device__ __forceinline__ float bf2f(unsigned short u) {
    return __uint_as_float((unsigned)u << 16);
}
__device__ __forceinline__ unsigned short key16(unsigned short u) { // order-preserving key
    return (u & 0x8000u) ? (unsigned short)(~u) : (unsigned short)(u | 0x8000u);
}
__device__ __forceinline__ float key2f16(unsigned key) {    // inverse: key -> float
    unsigned short b = (key & 0x8000u) ? (unsigned short)(key & 0x7FFFu)
                                       : (unsigned short)(~key & 0xFFFFu);
    return bf2f(b);
}
__device__ __forceinline__ void gload16(const void* g, void* l) {
    __builtin_amdgcn_global_load_lds(
        (const __attribute__((address_space(1))) unsigned int*)g,
        (__attribute__((address_space(3))) unsigned int*)l, 16, 0, 0);
}

// ---------------- fp32 -> bf16 pre-conversion (inputs + padded table) ----------------
#define NIN_G  (N_ROWS * DIM / 4)       // 262144 float4 granules
#define NTAB_G (TPAD * DIM / 4)         // 679936

__global__ __launch_bounds__(256) void convert_bf16(
    const float* __restrict__ inputs, const float* __restrict__ lut,
    const float* __restrict__ cq, unsigned short* __restrict__ in_bf,
    unsigned short* __restrict__ tab_bf)
{
    const int g = blockIdx.x * 256 + threadIdx.x;
    if (g >= NIN_G + NTAB_G) return;
    float4_t v;
    unsigned short* dst;
    if (g < NIN_G) {
        v = *(const float4_t*)&inputs[(size_t)g * 4];
        dst = in_bf + (size_t)g * 4;
    } else {
        const int t = g - NIN_G;
        const int row = t >> 6;                 // /(DIM/4)
        const int c4  = (t & 63) * 4;
        if (row < P_SZ)        v = *(const float4_t*)&lut[(size_t)row * DIM + c4];
        else if (row < C_COLS) v = *(const float4_t*)&cq[(size_t)(row - P_SZ) * DIM + c4];
        else                   v = (float4_t){0.f, 0.f, 0.f, 0.f};
        dst = tab_bf + (size_t)t * 4;
    }
    ushort4_t h = { f2bf(v.x), f2bf(v.y), f2bf(v.z), f2bf(v.w) };
    *(ushort4_t*)dst = h;
}

// ---------------- bf16 MFMA GEMM: proj(key16) = key16((in @ tab^T) * rel) ----------------
#define NWG_X 83
#define NWG_Y 32
#define NWG   (NWG_X * NWG_Y)   // 2656, divisible by 8
#define CSTR  132               // C-tile LDS row stride in elems (264 B, conflict-free)

__global__ __launch_bounds__(256) void gemm_proj(
    const unsigned short* __restrict__ in_bf,
    const unsigned short* __restrict__ tab_bf,
    const float* __restrict__ rel,
    unsigned short* __restrict__ proj)
{
    // union: K-loop stage tiles (2 x 16 KB) / epilogue C-tile (128 x 264 B)
    __shared__ __align__(16) unsigned short smem[128 * CSTR];   // 33792 B
    unsigned short* At = smem;                 // elem (r,k) at byte r*128 + ((k*2)^((r&7)<<4))
    unsigned short* Bt = smem + 128 * 64;

    const int tid  = threadIdx.x;
    const int lane = tid & 63, wid = tid >> 6;
    const int wm = wid >> 1, wn = wid & 1;

    // XCD-bijective swizzle, col-major decode: each XCD chunk keeps full A in L2
    const int phys = blockIdx.x;
    const int wg   = (phys & 7) * (NWG / 8) + (phys >> 3);
    const int bx   = wg >> 5;               // 0..82 col-block
    const int by   = wg & 31;               // 0..31 row-block
    const int row0 = by * 128, col0 = bx * 128;

    float4_t acc[4][4];
    #pragma unroll
    for (int i = 0; i < 4; ++i)
        #pragma unroll
        for (int j = 0; j < 4; ++j)
            acc[i][j] = (float4_t){0.f, 0.f, 0.f, 0.f};

    for (int k0 = 0; k0 < DIM; k0 += 64) {
        // stage: linear LDS dest + inverse-swizzled global source (16B granules)
        #pragma unroll
        for (int it = 0; it < 4; ++it) {
            const int g  = it * 256 + tid;       // granule: LDS byte = g*16
            const int r  = g >> 3;               // 0..127
            const int kb = ((g & 7) * 16) ^ ((r & 7) << 4);   // src byte within row
            gload16(in_bf  + (size_t)(row0 + r) * DIM + k0 + (kb >> 1),
                    (char*)At + g * 16);
            gload16(tab_bf + (size_t)(col0 + r) * DIM + k0 + (kb >> 1),
                    (char*)Bt + g * 16);
        }
        __syncthreads();

        #pragma unroll
        for (int kk = 0; kk < 2; ++kk) {
            const int krow = lane & 15;
            const int kb   = kk * 64 + ((lane >> 4) << 4);
            short8 af[4], bfr[4];
            #pragma unroll
            for (int i = 0; i < 4; ++i) {
                const int r = wm * 64 + i * 16 + krow;
                af[i] = *(const short8*)((const char*)At + (r * 128 + (kb ^ ((r & 7) << 4))));
            }
            #pragma unroll
            for (int j = 0; j < 4; ++j) {
                const int r = wn * 64 + j * 16 + krow;
                bfr[j] = *(const short8*)((const char*)Bt + (r * 128 + (kb ^ ((r & 7) << 4))));
            }
            #pragma unroll
            for (int i = 0; i < 4; ++i)
                #pragma unroll
                for (int j = 0; j < 4; ++j)
                    acc[i][j] = __builtin_amdgcn_mfma_f32_16x16x32_bf16(af[i], bfr[j], acc[i][j], 0, 0, 0);
        }
        __syncthreads();
    }

    // epilogue: C layout col=lane&15, row=(lane>>4)*4+rr  [m89]
    // stage key16(bf16 C) in LDS (row stride CSTR), then coalesced 16B stores
    const int lr = (lane >> 4) << 2;
    const int lc = lane & 15;
    #pragma unroll
    for (int j = 0; j < 4; ++j) {
        const int cl  = wn * 64 + j * 16 + lc;        // tile-local col
        const int col = col0 + cl;
        const bool pad = (col >= C_COLS);
        const float rl = pad ? 0.f : rel[col];
        #pragma unroll
        for (int i = 0; i < 4; ++i) {
            const int rbase = wm * 64 + i * 16 + lr;  // tile-local row
            #pragma unroll
            for (int rr = 0; rr < 4; ++rr)
                smem[(rbase + rr) * CSTR + cl] =
                    pad ? (unsigned short)0u : key16(f2bf(acc[i][j][rr] * rl));
        }
    }
    __syncthreads();
    // 128 rows x 256 B: granule g -> row g>>4, 16B chunk (g&15)
    #pragma unroll
    for (int it = 0; it < 8; ++it) {
        const int g = it * 256 + tid;
        const int r = g >> 4;
        const int c8 = (g & 15) * 8;                  // col in elems
        *(ushort8_t*)(proj + (size_t)(row0 + r) * PSTR + col0 + c8) =
            *(const ushort8_t*)&smem[r * CSTR + c8];
    }
}

// ---------------- per-row: 2-sweep radix select + masked LSE ----------------
// proj holds key16-transformed bf16 (monotone), so bin = key>>5 directly.
// Row lives in registers; LDS only for the (2-way privatized) count histogram.
__global__ __launch_bounds__(256) void row_loss_kernel(
    const unsigned short* __restrict__ proj, const int* __restrict__ labels,
    float* __restrict__ row_loss)
{
    __shared__ unsigned hist[2][2048];   // wave-pair privatized counts, key bits [15:5]
    __shared__ unsigned h2[32];
    __shared__ float    e2[32];
    __shared__ unsigned wsum[4];
    __shared__ float    fsum[4];
    __shared__ unsigned sel_bin, sel_k, sel_sub;
    __shared__ float    sel_minor;

    const int tid = threadIdx.x, lane = tid & 63, wid = tid >> 6;
    const int hsel = wid >> 1;
    const int row = blockIdx.x;
    const ushort8_t* prow = (const ushort8_t*)(proj + (size_t)row * PSTR);

    for (int i = tid; i < 4096; i += 256) hist[0][i] = 0;   // both copies
    if (tid < 32) { h2[tid] = 0; e2[tid] = 0.f; }
    __syncthreads();

    // ---- sweep 1: load row into registers + count histogram (native u32 atomics)
    ushort8_t r[6];
    #pragma unroll
    for (int it = 0; it < 6; ++it) {
        const int g = it * 256 + tid;
        if (it < 5 || g < NGR) {
            r[it] = prow[g];
            #pragma unroll
            for (int e = 0; e < 8; ++e)
                atomicAdd(&hist[hsel][r[it][e] >> 5], 1u);
        }
    }
    __syncthreads();

    // ---- scan: bin of the K_SEL-th largest + residual rank
    {
        const int t8 = tid * 8;
        unsigned cnt[8];
        unsigned s = 0;
        #pragma unroll
        for (int b = 0; b < 8; ++b) {
            cnt[b] = hist[0][t8 + b] + hist[1][t8 + b];
            s += cnt[b];
        }
        unsigned incl = s;
        #pragma unroll
        for (int off = 1; off < 64; off <<= 1) {
            const unsigned t = __shfl_down(incl, off, 64);
            if (lane + off < 64) incl += t;
        }
        if (lane == 0) wsum[wid] = incl;
        __syncthreads();
        unsigned cum = incl - s;                       // above within wave
        for (int w = wid + 1; w < 4; ++w) cum += wsum[w];
        #pragma unroll
        for (int b = 7; b >= 0; --b) {
            const unsigned c = cnt[b];
            if (cum < K_SEL && cum + c >= K_SEL) {
                sel_bin = (unsigned)(t8 + b); sel_k = K_SEL - cum;
            }
            cum += c;
        }
    }
    __syncthreads();
    const unsigned b1 = sel_bin;
    const unsigned k2 = sel_k;
    const unsigned klo = b1 << 5, khi = (b1 + 1) << 5;

    // ---- sweep 2 (registers): reg-accumulate exp above bin b1; tiny atomics in-bin
    float above = 0.f;
    #pragma unroll
    for (int it = 0; it < 6; ++it) {
        const int g = it * 256 + tid;
        if (it < 5 || g < NGR) {
            #pragma unroll
            for (int e = 0; e < 8; ++e) {
                const unsigned key = r[it][e];
                if (key >= khi) {
                    above += exp2f(C2 * (key2f16(key) - 1.0f));
                } else if (key >= klo) {
                    atomicAdd(&h2[key & 31u], 1u);
                    atomicAdd(&e2[key & 31u], exp2f(C2 * (key2f16(key) - 1.0f)));
                }
            }
        }
    }
    // block-reduce 'above'
    #pragma unroll
    for (int off = 1; off < 64; off <<= 1) {
        const float t = __shfl_down(above, off, 64);
        if (lane + off < 64) above += t;
    }
    if (lane == 0) fsum[wid] = above;
    __syncthreads();

    // ---- sub-scan: 32 bins, key bits [4:0]
    if (wid == 0) {
        const unsigned c = (lane < 32) ? h2[lane] : 0u;
        const float    f = (lane < 32) ? e2[lane] : 0.f;
        unsigned ic = c; float fc = f;
        #pragma unroll
        for (int off = 1; off < 64; off <<= 1) {
            const unsigned tc = __shfl_down(ic, off, 64);
            const float    tf = __shfl_down(fc, off, 64);
            if (lane + off < 64) { ic += tc; fc += tf; }
        }
        const unsigned abv = ic - c;
        if (lane < 32 && abv < k2 && abv + c >= k2) {
            sel_sub = (unsigned)lane; sel_minor = fc;   // inclusive: all ties masked
        }
    }
    __syncthreads();

    if (tid == 0) {
        const unsigned bkey = (b1 << 5) | sel_sub;
        float total = fsum[0] + fsum[1] + fsum[2] + fsum[3] + sel_minor;
        const unsigned ulk = ((const unsigned short*)prow)[labels[row]];  // label < P_SZ
        const float pl = key2f16(ulk);
        if (ulk < bkey) total += exp2f(C2 * (pl - 1.0f));
        row_loss[row] = SCALAR * 1.0f + logf(total) - SCALAR * pl;
    }
}

// ---------------- final mean ----------------
__global__ __launch_bounds__(256) void final_reduce(
    const float* __restrict__ row_loss, float* __restrict__ out)
{
    __shared__ float fred[4];
    const int tid = threadIdx.x, lane = tid & 63, wid = tid >> 6;
    float s = 0.f;
    for (int i = tid; i < N_ROWS; i += 256) s += row_loss[i];
    #pragma unroll
    for (int off = 1; off < 64; off <<= 1) {
        const float t = __shfl_down(s, off, 64);
        if (lane + off < 64) s += t;
    }
    if (lane == 0) fred[wid] = s;
    __syncthreads();
    if (tid == 0) out[0] = (fred[0] + fred[1] + fred[2] + fred[3]) / (float)N_ROWS;
}

extern "C" void kernel_launch(void* const* d_in, const int* in_sizes, int n_in,
                              void* d_out, int out_size, void* d_ws, size_t ws_size,
                              hipStream_t stream) {
    const float* inputs = (const float*)d_in[0];
    const int*   labels = (const int*)d_in[1];
    const float* lut    = (const float*)d_in[2];
    const float* cq     = (const float*)d_in[3];
    const float* rel    = (const float*)d_in[4];
    float* out = (float*)d_out;

    // ws: in_bf [4096*256] | tab_bf [10624*256] | proj [4096*10624] u16 | row_loss
    unsigned short* in_bf  = (unsigned short*)d_ws;
    unsigned short* tab_bf = in_bf  + (size_t)N_ROWS * DIM;
    unsigned short* proj   = tab_bf + (size_t)TPAD * DIM;
    float* rl_buf = (float*)(proj + (size_t)N_ROWS * PSTR);

    convert_bf16<<<(NIN_G + NTAB_G) / 256, 256, 0, stream>>>(inputs, lut, cq, in_bf, tab_bf);
    gemm_proj<<<NWG, 256, 0, stream>>>(in_bf, tab_bf, rel, proj);
    row_loss_kernel<<<N_ROWS, 256, 0, stream>>>(proj, labels, rl_buf);
    final_reduce<<<1, 256, 0, stream>>>(rl_buf, out);
}

// Round 7
// 97.587 us; speedup vs baseline: 3.1831x; 1.0609x over previous
//
#include <hip/hip_runtime.h>
#include <math.h>

#define N_ROWS 4096
#define DIM    256
#define P_SZ   5532
#define Q_SZ   5000
#define C_COLS 10532            // P+Q
#define TPAD   10624            // table rows padded to 83*128 (zero-filled)
#define PSTR   10624            // proj row stride in u16 elems == TPAD (full tiles)
#define NGR    (PSTR / 8)       // 1328 ushort8 granules per proj row
#define NDW    (PSTR / 4)       // 2656 dwords per proj row
#define K_SEL  701              // HARD_NUM + 1
#define SCALAR 30.0f
#define C2     (SCALAR * 1.4426950408889634f)   // log2(e)*30

typedef __attribute__((ext_vector_type(8))) short   short8;
typedef __attribute__((ext_vector_type(4))) float   float4_t;
typedef __attribute__((ext_vector_type(4))) unsigned short ushort4_t;
typedef __attribute__((ext_vector_type(8))) unsigned short ushort8_t;
typedef __attribute__((ext_vector_type(4))) unsigned int  uint4_t;

// ---------------- helpers ----------------
__device__ __forceinline__ unsigned short f2bf(float f) {   // fp32 -> bf16 RNE
    unsigned u = __float_as_uint(f);
    unsigned r = u + 0x7FFFu + ((u >> 16) & 1u);
    return (unsigned short)(r >> 16);
}
__device__ __forceinline__ float bf2f(unsigned short u) {
    return __uint_as_float((unsigned)u << 16);
}
__device__ __forceinline__ unsigned short key16(unsigned short u) { // order-preserving key
    return (u & 0x8000u) ? (unsigned short)(~u) : (unsigned short)(u | 0x8000u);
}
__device__ __forceinline__ float key2f16(unsigned key) {    // inverse: key -> float
    unsigned short b = (key & 0x8000u) ? (unsigned short)(key & 0x7FFFu)
                                       : (unsigned short)(~key & 0xFFFFu);
    return bf2f(b);
}
__device__ __forceinline__ void gload16(const void* g, void* l) {
    __builtin_amdgcn_global_load_lds(
        (const __attribute__((address_space(1))) unsigned int*)g,
        (__attribute__((address_space(3))) unsigned int*)l, 16, 0, 0);
}

// ---------------- fp32 -> bf16 pre-conversion (inputs + padded table) ----------------
#define NIN_G  (N_ROWS * DIM / 4)       // 262144 float4 granules
#define NTAB_G (TPAD * DIM / 4)         // 679936

__global__ __launch_bounds__(256) void convert_bf16(
    const float* __restrict__ inputs, const float* __restrict__ lut,
    const float* __restrict__ cq, unsigned short* __restrict__ in_bf,
    unsigned short* __restrict__ tab_bf)
{
    const int g = blockIdx.x * 256 + threadIdx.x;
    if (g >= NIN_G + NTAB_G) return;
    float4_t v;
    unsigned short* dst;
    if (g < NIN_G) {
        v = *(const float4_t*)&inputs[(size_t)g * 4];
        dst = in_bf + (size_t)g * 4;
    } else {
        const int t = g - NIN_G;
        const int row = t >> 6;                 // /(DIM/4)
        const int c4  = (t & 63) * 4;
        if (row < P_SZ)        v = *(const float4_t*)&lut[(size_t)row * DIM + c4];
        else if (row < C_COLS) v = *(const float4_t*)&cq[(size_t)(row - P_SZ) * DIM + c4];
        else                   v = (float4_t){0.f, 0.f, 0.f, 0.f};
        dst = tab_bf + (size_t)t * 4;
    }
    ushort4_t h = { f2bf(v.x), f2bf(v.y), f2bf(v.z), f2bf(v.w) };
    *(ushort4_t*)dst = h;
}

// ---------------- bf16 MFMA GEMM: proj(key16) = key16((in @ tab^T) * rel) ----------------
#define NWG_X 83
#define NWG_Y 32
#define NWG   (NWG_X * NWG_Y)   // 2656, divisible by 8
#define CSTR  132               // C-tile LDS row stride in elems (264 B, conflict-free)

__global__ __launch_bounds__(256) void gemm_proj(
    const unsigned short* __restrict__ in_bf,
    const unsigned short* __restrict__ tab_bf,
    const float* __restrict__ rel,
    unsigned short* __restrict__ proj)
{
    // union: K-loop stage tiles (2 x 16 KB) / epilogue C-tile (128 x 264 B)
    __shared__ __align__(16) unsigned short smem[128 * CSTR];   // 33792 B
    unsigned short* At = smem;                 // elem (r,k) at byte r*128 + ((k*2)^((r&7)<<4))
    unsigned short* Bt = smem + 128 * 64;

    const int tid  = threadIdx.x;
    const int lane = tid & 63, wid = tid >> 6;
    const int wm = wid >> 1, wn = wid & 1;

    // XCD-bijective swizzle, col-major decode: each XCD chunk keeps full A in L2
    const int phys = blockIdx.x;
    const int wg   = (phys & 7) * (NWG / 8) + (phys >> 3);
    const int bx   = wg >> 5;               // 0..82 col-block
    const int by   = wg & 31;               // 0..31 row-block
    const int row0 = by * 128, col0 = bx * 128;

    float4_t acc[4][4];
    #pragma unroll
    for (int i = 0; i < 4; ++i)
        #pragma unroll
        for (int j = 0; j < 4; ++j)
            acc[i][j] = (float4_t){0.f, 0.f, 0.f, 0.f};

    for (int k0 = 0; k0 < DIM; k0 += 64) {
        // stage: linear LDS dest + inverse-swizzled global source (16B granules)
        #pragma unroll
        for (int it = 0; it < 4; ++it) {
            const int g  = it * 256 + tid;       // granule: LDS byte = g*16
            const int r  = g >> 3;               // 0..127
            const int kb = ((g & 7) * 16) ^ ((r & 7) << 4);   // src byte within row
            gload16(in_bf  + (size_t)(row0 + r) * DIM + k0 + (kb >> 1),
                    (char*)At + g * 16);
            gload16(tab_bf + (size_t)(col0 + r) * DIM + k0 + (kb >> 1),
                    (char*)Bt + g * 16);
        }
        __syncthreads();

        #pragma unroll
        for (int kk = 0; kk < 2; ++kk) {
            const int krow = lane & 15;
            const int kb   = kk * 64 + ((lane >> 4) << 4);
            short8 af[4], bfr[4];
            #pragma unroll
            for (int i = 0; i < 4; ++i) {
                const int r = wm * 64 + i * 16 + krow;
                af[i] = *(const short8*)((const char*)At + (r * 128 + (kb ^ ((r & 7) << 4))));
            }
            #pragma unroll
            for (int j = 0; j < 4; ++j) {
                const int r = wn * 64 + j * 16 + krow;
                bfr[j] = *(const short8*)((const char*)Bt + (r * 128 + (kb ^ ((r & 7) << 4))));
            }
            #pragma unroll
            for (int i = 0; i < 4; ++i)
                #pragma unroll
                for (int j = 0; j < 4; ++j)
                    acc[i][j] = __builtin_amdgcn_mfma_f32_16x16x32_bf16(af[i], bfr[j], acc[i][j], 0, 0, 0);
        }
        __syncthreads();
    }

    // epilogue: C layout col=lane&15, row=(lane>>4)*4+rr  [m89]
    // stage key16(bf16 C) in LDS (row stride CSTR), then coalesced 16B stores
    const int lr = (lane >> 4) << 2;
    const int lc = lane & 15;
    #pragma unroll
    for (int j = 0; j < 4; ++j) {
        const int cl  = wn * 64 + j * 16 + lc;        // tile-local col
        const int col = col0 + cl;
        const bool pad = (col >= C_COLS);
        const float rl = pad ? 0.f : rel[col];
        #pragma unroll
        for (int i = 0; i < 4; ++i) {
            const int rbase = wm * 64 + i * 16 + lr;  // tile-local row
            #pragma unroll
            for (int rr = 0; rr < 4; ++rr)
                smem[(rbase + rr) * CSTR + cl] =
                    pad ? (unsigned short)0u : key16(f2bf(acc[i][j][rr] * rl));
        }
    }
    __syncthreads();
    // 128 rows x 256 B: granule g -> row g>>4, 16B chunk (g&15)
    #pragma unroll
    for (int it = 0; it < 8; ++it) {
        const int g = it * 256 + tid;
        const int r = g >> 4;
        const int c8 = (g & 15) * 8;                  // col in elems
        *(ushort8_t*)(proj + (size_t)(row0 + r) * PSTR + col0 + c8) =
            *(const ushort8_t*)&smem[r * CSTR + c8];
    }
}

// ---------------- per-row: 2-pass radix select (8+8 bits) + masked LSE ----------------
// proj holds key16 (monotone). Pass 1: 256 bins (bits[15:8]), 16-way lane-privatized
// (stride 257 => copies of a bin in 16 distinct banks). Pass 2: 256 sub-bins among
// boundary-bin elements only. Pass 3: deterministic masked exp sweep. Count-only
// LDS atomics; no float atomics; fixed reduction order.
#define NCPY 16
__global__ __launch_bounds__(256) void row_loss_kernel(
    const unsigned short* __restrict__ proj, const int* __restrict__ labels,
    float* __restrict__ row_loss)
{
    __shared__ unsigned h1[NCPY * 257];   // 16448 B
    __shared__ unsigned h2[256];
    __shared__ unsigned wsum[4];
    __shared__ float    fsum[4];
    __shared__ unsigned sel_bin, sel_k, sel_sub;

    const int tid = threadIdx.x, lane = tid & 63, wid = tid >> 6;
    const int row = blockIdx.x;
    const uint4_t* prow = (const uint4_t*)(proj + (size_t)row * PSTR);
    const unsigned cbase = (unsigned)(tid & (NCPY - 1)) * 257;

    for (int i = tid; i < NCPY * 257; i += 256) h1[i] = 0;
    if (tid < 256) h2[tid] = 0;
    __syncthreads();

    // ---- sweep 1: 256-bin histogram on key bits [15:8] (privatized)
    #pragma unroll
    for (int it = 0; it < 5; ++it) {
        const uint4_t w = prow[it * 256 + tid];
        #pragma unroll
        for (int d = 0; d < 4; ++d) {
            atomicAdd(&h1[cbase + ((w[d] >> 8) & 0xFFu)], 1u);
            atomicAdd(&h1[cbase + (w[d] >> 24)], 1u);
        }
    }
    if (tid < NGR - 1280) {                       // tail granules
        const uint4_t w = prow[1280 + tid];
        #pragma unroll
        for (int d = 0; d < 4; ++d) {
            atomicAdd(&h1[cbase + ((w[d] >> 8) & 0xFFu)], 1u);
            atomicAdd(&h1[cbase + (w[d] >> 24)], 1u);
        }
    }
    __syncthreads();

    // ---- scan 1: thread t owns bin t; suffix-from-top; find boundary bin
    {
        unsigned c = 0;
        #pragma unroll
        for (int cp = 0; cp < NCPY; ++cp) c += h1[cp * 257 + tid];
        unsigned incl = c;
        #pragma unroll
        for (int off = 1; off < 64; off <<= 1) {
            const unsigned t = __shfl_down(incl, off, 64);
            if (lane + off < 64) incl += t;
        }
        if (lane == 0) wsum[wid] = incl;
        __syncthreads();
        unsigned above = incl - c;
        for (int w = wid + 1; w < 4; ++w) above += wsum[w];
        if (above < K_SEL && above + c >= K_SEL) {
            sel_bin = (unsigned)tid; sel_k = K_SEL - above;
        }
    }
    __syncthreads();
    const unsigned b1 = sel_bin;
    const unsigned k2 = sel_k;
    __syncthreads();

    // ---- sweep 2: sub-histogram (low byte) among bin-b1 elements only
    #pragma unroll
    for (int it = 0; it < 5; ++it) {
        const uint4_t w = prow[it * 256 + tid];
        #pragma unroll
        for (int d = 0; d < 4; ++d) {
            const unsigned lo = w[d] & 0xFFFFu, hi = w[d] >> 16;
            if ((lo >> 8) == b1) atomicAdd(&h2[lo & 0xFFu], 1u);
            if ((hi >> 8) == b1) atomicAdd(&h2[hi & 0xFFu], 1u);
        }
    }
    if (tid < NGR - 1280) {
        const uint4_t w = prow[1280 + tid];
        #pragma unroll
        for (int d = 0; d < 4; ++d) {
            const unsigned lo = w[d] & 0xFFFFu, hi = w[d] >> 16;
            if ((lo >> 8) == b1) atomicAdd(&h2[lo & 0xFFu], 1u);
            if ((hi >> 8) == b1) atomicAdd(&h2[hi & 0xFFu], 1u);
        }
    }
    __syncthreads();

    // ---- scan 2: find sub-bin -> exact boundary key
    {
        const unsigned c = h2[tid];
        unsigned incl = c;
        #pragma unroll
        for (int off = 1; off < 64; off <<= 1) {
            const unsigned t = __shfl_down(incl, off, 64);
            if (lane + off < 64) incl += t;
        }
        if (lane == 0) wsum[wid] = incl;
        __syncthreads();
        unsigned above = incl - c;
        for (int w = wid + 1; w < 4; ++w) above += wsum[w];
        if (above < k2 && above + c >= k2) sel_sub = (unsigned)tid;
    }
    __syncthreads();
    const unsigned bkey = (b1 << 8) | sel_sub;

    // ---- sweep 3: masked exp sum (deterministic order)
    float s = 0.f;
    #pragma unroll
    for (int it = 0; it < 5; ++it) {
        const uint4_t w = prow[it * 256 + tid];
        #pragma unroll
        for (int d = 0; d < 4; ++d) {
            const unsigned lo = w[d] & 0xFFFFu, hi = w[d] >> 16;
            if (lo >= bkey) s += exp2f(C2 * key2f16(lo) - C2);
            if (hi >= bkey) s += exp2f(C2 * key2f16(hi) - C2);
        }
    }
    if (tid < NGR - 1280) {
        const uint4_t w = prow[1280 + tid];
        #pragma unroll
        for (int d = 0; d < 4; ++d) {
            const unsigned lo = w[d] & 0xFFFFu, hi = w[d] >> 16;
            if (lo >= bkey) s += exp2f(C2 * key2f16(lo) - C2);
            if (hi >= bkey) s += exp2f(C2 * key2f16(hi) - C2);
        }
    }
    #pragma unroll
    for (int off = 1; off < 64; off <<= 1) {
        const float t = __shfl_down(s, off, 64);
        if (lane + off < 64) s += t;
    }
    if (lane == 0) fsum[wid] = s;
    __syncthreads();

    if (tid == 0) {
        float total = fsum[0] + fsum[1] + fsum[2] + fsum[3];
        const unsigned ulk = ((const unsigned short*)prow)[labels[row]];  // label < P_SZ
        const float pl = key2f16(ulk);
        if (ulk < bkey) total += exp2f(C2 * pl - C2);
        row_loss[row] = SCALAR * 1.0f + logf(total) - SCALAR * pl;
    }
}

// ---------------- final mean ----------------
__global__ __launch_bounds__(256) void final_reduce(
    const float* __restrict__ row_loss, float* __restrict__ out)
{
    __shared__ float fred[4];
    const int tid = threadIdx.x, lane = tid & 63, wid = tid >> 6;
    float s = 0.f;
    for (int i = tid; i < N_ROWS; i += 256) s += row_loss[i];
    #pragma unroll
    for (int off = 1; off < 64; off <<= 1) {
        const float t = __shfl_down(s, off, 64);
        if (lane + off < 64) s += t;
    }
    if (lane == 0) fred[wid] = s;
    __syncthreads();
    if (tid == 0) out[0] = (fred[0] + fred[1] + fred[2] + fred[3]) / (float)N_ROWS;
}

extern "C" void kernel_launch(void* const* d_in, const int* in_sizes, int n_in,
                              void* d_out, int out_size, void* d_ws, size_t ws_size,
                              hipStream_t stream) {
    const float* inputs = (const float*)d_in[0];
    const int*   labels = (const int*)d_in[1];
    const float* lut    = (const float*)d_in[2];
    const float* cq     = (const float*)d_in[3];
    const float* rel    = (const float*)d_in[4];
    float* out = (float*)d_out;

    // ws: in_bf [4096*256] | tab_bf [10624*256] | proj [4096*10624] u16 | row_loss
    unsigned short* in_bf  = (unsigned short*)d_ws;
    unsigned short* tab_bf = in_bf  + (size_t)N_ROWS * DIM;
    unsigned short* proj   = tab_bf + (size_t)TPAD * DIM;
    float* rl_buf = (float*)(proj + (size_t)N_ROWS * PSTR);

    convert_bf16<<<(NIN_G + NTAB_G) / 256, 256, 0, stream>>>(inputs, lut, cq, in_bf, tab_bf);
    gemm_proj<<<NWG, 256, 0, stream>>>(in_bf, tab_bf, rel, proj);
    row_loss_kernel<<<N_ROWS, 256, 0, stream>>>(proj, labels, rl_buf);
    final_reduce<<<1, 256, 0, stream>>>(rl_buf, out);
}